// Round 11
// baseline (155.690 us; speedup 1.0000x reference)
//
#include <hip/hip_runtime.h>

typedef __bf16 bf16;
typedef __bf16 bf16x8 __attribute__((ext_vector_type(8)));
typedef __bf16 bf16x4 __attribute__((ext_vector_type(4)));
typedef float  f32x4  __attribute__((ext_vector_type(4)));

#define NND   2048      // nodes
#define NBB   8         // batch
#define NPADC 576       // padded panel rows (>= 528, mult of 64)
#define KEXP  3328      // expanded K: 208 ki-chunks * 16 d
#define MTOT  16384     // B*N

__device__ __forceinline__ float sigf(float v) { return 1.f / (1.f + __expf(-v)); }

__device__ __forceinline__ void gl_lds16(const bf16* g, bf16* l) {
  __builtin_amdgcn_global_load_lds(
      (const __attribute__((address_space(1))) void*)g,
      (__attribute__((address_space(3))) void*)l, 16, 0, 0);
}

__device__ __forceinline__ f32x4 up4(bf16x4 v) {
  return __builtin_convertvector(v, f32x4);
}

// ---------------------------------------------------------------
// misc_kernel: grid-fused prep_w (156) + adj (256) + pack (256)
// ---------------------------------------------------------------
#define PREP_BLKS 156
#define ADJ_BLKS  256
#define PACK_BLKS 256

__global__ __launch_bounds__(256)
void misc_kernel(const float* __restrict__ E, const float* __restrict__ x,
                 const float* __restrict__ state,
                 const float* __restrict__ WpG, const float* __restrict__ BpG,
                 const float* __restrict__ WpU, const float* __restrict__ BpU,
                 bf16* __restrict__ Sbf, bf16* __restrict__ XT,
                 bf16* __restrict__ candT, bf16* __restrict__ BTg,
                 bf16* __restrict__ BTu) {
  __shared__ float tile[66][65];
  int bid = blockIdx.x;
  int t = threadIdx.x;

  if (bid < PREP_BLKS) {
    int which = bid / 52;
    int k0 = (bid % 52) * 64;
    const float* Wp; const float* Bp; bf16* BT; int ncols, o0;
    if (which < 2) { Wp = WpG; Bp = BpG; BT = BTg; ncols = 128; o0 = which * 64; }
    else           { Wp = WpU; Bp = BpU; BT = BTu; ncols = 64;  o0 = 0; }
    for (int idx = t; idx < 4096; idx += 256) {
      int kr = idx >> 6, oc = idx & 63;
      int kp = k0 + kr;
      int ki = kp >> 4, d = kp & 15;
      float v;
      if (ki < 198) {
        int kc3 = ki / 66;
        int i = ki - kc3 * 66;
        v = Wp[(size_t)((d * 3 + kc3) * 66 + i) * ncols + o0 + oc];
      } else if (ki == 198) {
        v = Bp[d * ncols + o0 + oc];
      } else {
        v = 0.f;
      }
      tile[kr][oc] = v;
    }
    __syncthreads();
    for (int idx = t; idx < 4096; idx += 256) {
      int orow = idx >> 6, kc = idx & 63;
      BT[(size_t)(o0 + orow) * KEXP + k0 + kc] = (bf16)tile[kc][orow];
    }
  } else if (bid < PREP_BLKS + ADJ_BLKS) {
    // adj: S = softmax(relu(E E^T)), 8 rows/block
    int r0 = (bid - PREP_BLKS) * 8;
    int lane = t & 63, w = t >> 6;
    float* red = &tile[0][0];
    float er[8][16];
#pragma unroll
    for (int r = 0; r < 8; ++r) {
      const f32x4* ep = (const f32x4*)(E + (size_t)(r0 + r) * 16);
#pragma unroll
      for (int qi = 0; qi < 4; ++qi) {
        f32x4 q = ep[qi];
#pragma unroll
        for (int j = 0; j < 4; ++j) er[r][qi * 4 + j] = q[j];
      }
    }
    float v[8][8];
    float mx[8];
#pragma unroll
    for (int r = 0; r < 8; ++r) mx[r] = 0.f;
#pragma unroll
    for (int j = 0; j < 8; ++j) {
      int c = t + j * 256;
      const f32x4* cp = (const f32x4*)(E + (size_t)c * 16);
      float ec[16];
#pragma unroll
      for (int qi = 0; qi < 4; ++qi) {
        f32x4 q = cp[qi];
#pragma unroll
        for (int jj = 0; jj < 4; ++jj) ec[qi * 4 + jj] = q[jj];
      }
#pragma unroll
      for (int r = 0; r < 8; ++r) {
        float s = 0.f;
#pragma unroll
        for (int d = 0; d < 16; ++d) s += er[r][d] * ec[d];
        s = fmaxf(s, 0.f);
        v[r][j] = s;
        mx[r] = fmaxf(mx[r], s);
      }
    }
#pragma unroll
    for (int o = 32; o > 0; o >>= 1)
#pragma unroll
      for (int r = 0; r < 8; ++r) mx[r] = fmaxf(mx[r], __shfl_xor(mx[r], o, 64));
    if (lane == 0)
#pragma unroll
      for (int r = 0; r < 8; ++r) red[w * 8 + r] = mx[r];
    __syncthreads();
#pragma unroll
    for (int r = 0; r < 8; ++r)
      mx[r] = fmaxf(fmaxf(red[r], red[8 + r]), fmaxf(red[16 + r], red[24 + r]));
    float sm[8];
#pragma unroll
    for (int r = 0; r < 8; ++r) sm[r] = 0.f;
#pragma unroll
    for (int j = 0; j < 8; ++j)
#pragma unroll
      for (int r = 0; r < 8; ++r) { v[r][j] = __expf(v[r][j] - mx[r]); sm[r] += v[r][j]; }
#pragma unroll
    for (int o = 32; o > 0; o >>= 1)
#pragma unroll
      for (int r = 0; r < 8; ++r) sm[r] += __shfl_xor(sm[r], o, 64);
    __syncthreads();
    if (lane == 0)
#pragma unroll
      for (int r = 0; r < 8; ++r) red[32 + w * 8 + r] = sm[r];
    __syncthreads();
#pragma unroll
    for (int r = 0; r < 8; ++r) {
      float inv = 1.f / (red[32 + r] + red[40 + r] + red[48 + r] + red[56 + r]);
#pragma unroll
      for (int j = 0; j < 8; ++j)
        Sbf[(size_t)(r0 + r) * NND + t + j * 256] = (bf16)(v[r][j] * inv);
    }
  } else {
    // pack: XT[(b*66+c)][n] = concat(x,state); x-rows also -> candT
    int pb = bid - PREP_BLKS - ADJ_BLKS;
    int b  = pb >> 5;
    int n0 = (pb & 31) * 64;
    for (int idx = t; idx < 66 * 64; idx += 256) {
      int nn = idx / 66;
      int c  = idx - nn * 66;
      int bn = (b << 11) + n0 + nn;
      float v = (c < 2) ? x[bn * 2 + c] : state[(bn << 6) + c - 2];
      tile[c][nn] = v;
    }
    __syncthreads();
    for (int idx = t; idx < 66 * 64; idx += 256) {
      int c = idx >> 6;
      int nn = idx & 63;
      bf16 v = (bf16)tile[c][nn];
      size_t off = (size_t)(b * 66 + c) * NND + n0 + nn;
      XT[off] = v;
      if (c < 2) candT[off] = v;
    }
  }
}

// ---------------------------------------------------------------
// graph GEMM partials (bf16): P[z][c][n] = sum_{z-quarter} S[n][k]*B[c][k]
// 128(n) x 64(c) tile, BK=64, gl_lds + XOR swizzle, dbuf, 1 barrier/step.
// 1D grid 576 with XCD chunk swizzle, m-major.
// ---------------------------------------------------------------
__global__ __launch_bounds__(256)
void gemm_kernel(const bf16* __restrict__ A, const bf16* __restrict__ Bbf,
                 bf16* __restrict__ P) {
  __shared__ bf16 As[2][128 * 64];
  __shared__ bf16 Bs[2][64 * 64];
  int t = threadIdx.x;
  int wg = (blockIdx.x & 7) * 72 + (blockIdx.x >> 3);   // 576 = 8*72, bijective
  int m  = wg / 36;
  int rem = wg - m * 36;
  int m0 = m * 128;
  int c0 = (rem >> 2) * 64;
  int z  = rem & 3;
  int lane = t & 63, w = t >> 6;
  int wr = w >> 1, wc = w & 1;
  int row16 = lane & 15, kq = (lane >> 4) << 3;
  int kbase = z * 512;

  f32x4 acc[4][2] = {};

  auto stage = [&](int k0, int bb) {
#pragma unroll
    for (int i = 0; i < 4; ++i) {
      int s = i * 256 + t;
      int row = s >> 3;
      int g = ((s & 7) ^ (row & 7)) << 3;
      gl_lds16(A + (size_t)(m0 + row) * NND + k0 + g, &As[bb][s * 8]);
    }
#pragma unroll
    for (int i = 0; i < 2; ++i) {
      int s = i * 256 + t;
      int row = s >> 3;
      int g = ((s & 7) ^ (row & 7)) << 3;
      gl_lds16(Bbf + (size_t)(c0 + row) * NND + k0 + g, &Bs[bb][s * 8]);
    }
  };
  auto mstep = [&](int bb) {
#pragma unroll
    for (int kk2 = 0; kk2 < 64; kk2 += 32) {
      int kcg = (kk2 + kq) >> 3;
      bf16x8 af[4], bfg[2];
#pragma unroll
      for (int mi = 0; mi < 4; ++mi) {
        int row = wr * 64 + mi * 16 + row16;
        af[mi] = *(const bf16x8*)&As[bb][row * 64 + ((kcg ^ (row & 7)) << 3)];
      }
#pragma unroll
      for (int ni = 0; ni < 2; ++ni) {
        int row = wc * 32 + ni * 16 + row16;
        bfg[ni] = *(const bf16x8*)&Bs[bb][row * 64 + ((kcg ^ (row & 7)) << 3)];
      }
#pragma unroll
      for (int mi = 0; mi < 4; ++mi)
#pragma unroll
        for (int ni = 0; ni < 2; ++ni)
          acc[mi][ni] = __builtin_amdgcn_mfma_f32_16x16x32_bf16(af[mi], bfg[ni], acc[mi][ni], 0, 0, 0);
    }
  };

  stage(kbase, 0);
  __syncthreads();
  int buf = 0;
  for (int s = 0; s < 8; ++s) {
    if (s < 7) stage(kbase + (s + 1) * 64, buf ^ 1);
    mstep(buf);
    __syncthreads();
    buf ^= 1;
  }

#pragma unroll
  for (int mi = 0; mi < 4; ++mi)
#pragma unroll
    for (int ni = 0; ni < 2; ++ni) {
      int nb = m0 + wr * 64 + mi * 16 + ((lane >> 4) << 2);
      int oc = c0 + wc * 32 + ni * 16 + (lane & 15);
      bf16x4 pb = __builtin_convertvector(acc[mi][ni], bf16x4);
      *(bf16x4*)&P[((size_t)z * NPADC + oc) * NND + nb] = pb;
    }
}

// ---------------------------------------------------------------
// reduce 4 bf16 planes -> bf16. grid 576, 8 elems/thread.
// ---------------------------------------------------------------
__global__ __launch_bounds__(256)
void reduce_kernel(const bf16* __restrict__ P, bf16* __restrict__ Y) {
  size_t i = ((size_t)blockIdx.x * 256 + threadIdx.x) * 8;
  const size_t PL = (size_t)NPADC * NND;
  bf16x8 p0 = *(const bf16x8*)&P[i];
  bf16x8 p1 = *(const bf16x8*)&P[PL + i];
  bf16x8 p2 = *(const bf16x8*)&P[2 * PL + i];
  bf16x8 p3 = *(const bf16x8*)&P[3 * PL + i];
  bf16x8 o;
#pragma unroll
  for (int j = 0; j < 8; ++j)
    o[j] = (bf16)(((float)p0[j] + (float)p1[j]) + ((float)p2[j] + (float)p3[j]));
  *(bf16x8*)&Y[i] = o;
}

// ---------------------------------------------------------------
// wgemm partials (bf16): Pg[z][oc][bn] = sum_{z-quarter} A'[bn][k]*B'[k][oc]
// A'[bn][ki*16+d] = xg(bn,ki)*E[n][d] built in LDS (swizzled ds_write).
// 128(bn) x 64(oc) tile (A-frag reuse 4), BK=64, 13 steps, ONE barrier
// per step, 48KB LDS (3 blocks/CU). 1D grid with XCD swizzle:
// gate 1024 blocks, update 512.
// ---------------------------------------------------------------
template<int NCOLS>
__global__ __launch_bounds__(256)
void wgemm_kernel(const bf16* __restrict__ XTsrc, const bf16* __restrict__ Y1,
                  const bf16* __restrict__ Y2, const float* __restrict__ E,
                  const bf16* __restrict__ BT, bf16* __restrict__ Pg) {
  constexpr int YB  = NCOLS / 64;
  constexpr int NWG = (MTOT / 128) * YB * 4;
  __shared__ bf16 As[2][128 * 64];
  __shared__ bf16 Bs[2][64 * 64];
  int t = threadIdx.x;
  int wg = (blockIdx.x & 7) * (NWG >> 3) + (blockIdx.x >> 3);
  int z  = wg & 3;
  int y  = (wg >> 2) % YB;
  int m0 = (wg / (4 * YB)) * 128;
  int oc0 = y * 64;
  const bf16* BTb = BT + (size_t)oc0 * KEXP;
  int lane = t & 63, w = t >> 6;
  int wr = w >> 1, wc = w & 1;
  int row16 = lane & 15, kq = (lane >> 4) << 3;
  int r = t & 127, kh = t >> 7;            // expansion: row r (0..127), k-half kh (0..1)
  int bn = m0 + r, bidx = bn >> 11, n = bn & 2047;
  const int kbase = z * 832, kibase = z * 52;

  float e[16];
  {
    const f32x4* ep = (const f32x4*)(E + (size_t)n * 16);
#pragma unroll
    for (int qi = 0; qi < 4; ++qi) {
      f32x4 q = ep[qi];
#pragma unroll
      for (int j = 0; j < 4; ++j) e[qi * 4 + j] = q[j];
    }
  }

  f32x4 acc[4][2] = {};

  auto loadx = [&](int ki) -> float {
    if (ki < 66)  return (float)XTsrc[(size_t)(bidx * 66 + ki) * NND + n];
    if (ki < 132) return (float)Y1[(size_t)(bidx * 66 + ki - 66) * NND + n];
    if (ki < 198) {
      size_t off = (size_t)(bidx * 66 + ki - 132) * NND + n;
      return 2.f * (float)Y2[off] - (float)XTsrc[off];
    }
    return (ki == 198) ? 1.f : 0.f;
  };
  auto expand = [&](int bb, float xv0, float xv1) {
#pragma unroll
    for (int p = 0; p < 2; ++p) {
      float xv = p ? xv1 : xv0;
#pragma unroll
      for (int q = 0; q < 2; ++q) {
        bf16x8 pk;
#pragma unroll
        for (int j = 0; j < 8; ++j) pk[j] = (bf16)(xv * e[q * 8 + j]);
        int g = kh * 4 + p * 2 + q;
        *(bf16x8*)&As[bb][r * 64 + ((g ^ (r & 7)) << 3)] = pk;
      }
    }
  };
  auto stageB = [&](int k0, int bb) {
#pragma unroll
    for (int i = 0; i < 2; ++i) {
      int s = i * 256 + t;
      int row = s >> 3;
      int g = ((s & 7) ^ (row & 7)) << 3;
      gl_lds16(BTb + (size_t)row * KEXP + k0 + g, &Bs[bb][s * 8]);
    }
  };
  auto mstep = [&](int bb) {
#pragma unroll
    for (int kk2 = 0; kk2 < 64; kk2 += 32) {
      int kcg = (kk2 + kq) >> 3;
      bf16x8 af[4], bfg[2];
#pragma unroll
      for (int mi = 0; mi < 4; ++mi) {
        int row = wr * 64 + mi * 16 + row16;
        af[mi] = *(const bf16x8*)&As[bb][row * 64 + ((kcg ^ (row & 7)) << 3)];
      }
#pragma unroll
      for (int ni = 0; ni < 2; ++ni) {
        int row = wc * 32 + ni * 16 + row16;
        bfg[ni] = *(const bf16x8*)&Bs[bb][row * 64 + ((kcg ^ (row & 7)) << 3)];
      }
#pragma unroll
      for (int mi = 0; mi < 4; ++mi)
#pragma unroll
        for (int ni = 0; ni < 2; ++ni)
          acc[mi][ni] = __builtin_amdgcn_mfma_f32_16x16x32_bf16(af[mi], bfg[ni], acc[mi][ni], 0, 0, 0);
    }
  };

  // prologue: stage step 0 into buf 0
  {
    int kid = kibase + kh * 2;
    float x0 = loadx(kid), x1 = loadx(kid + 1);
    stageB(kbase, 0);
    expand(0, x0, x1);
  }
  __syncthreads();

  int buf = 0;
  for (int s = 0; s < 13; ++s) {
    float nx0 = 0.f, nx1 = 0.f;
    if (s < 12) {
      stageB(kbase + (s + 1) * 64, buf ^ 1);   // gl_lds into Bs[buf^1]
      int kid = kibase + (s + 1) * 4 + kh * 2;
      nx0 = loadx(kid);                        // xg for As[buf^1]
      nx1 = loadx(kid + 1);
    }
    mstep(buf);                                // reads As/Bs[buf] only
    if (s < 12) expand(buf ^ 1, nx0, nx1);     // ds_write As[buf^1] — no overlap
    __syncthreads();                           // one barrier/step
    buf ^= 1;
  }

#pragma unroll
  for (int mi = 0; mi < 4; ++mi)
#pragma unroll
    for (int ni = 0; ni < 2; ++ni) {
      int nb = m0 + wr * 64 + mi * 16 + ((lane >> 4) << 2);
      int oc = oc0 + wc * 32 + ni * 16 + (lane & 15);
      bf16x4 pb = __builtin_convertvector(acc[mi][ni], bf16x4);
      *(bf16x4*)&Pg[((size_t)z * NCOLS + oc) * MTOT + nb] = pb;
    }
}

// ---------------------------------------------------------------
// gate epilogue (4 bf16 planes): zT = sig(sum); candT = sig(sum)*state
// grid = MTOT/64
// ---------------------------------------------------------------
__global__ __launch_bounds__(256)
void gate_epi(const bf16* __restrict__ P, const float* __restrict__ state,
              float* __restrict__ zT, bf16* __restrict__ candT) {
  __shared__ float st[64][65];
  int bn0 = blockIdx.x * 64;
  int t = threadIdx.x;
#pragma unroll
  for (int i = 0; i < 16; ++i) {
    int e = i * 256 + t;
    int bnr = e >> 6, hc = e & 63;
    st[hc][bnr] = state[(size_t)(bn0 + bnr) * 64 + hc];
  }
  __syncthreads();
#pragma unroll
  for (int i = 0; i < 4; ++i) {
    int pr = i * 256 + t;
    int h = pr >> 4, bl = (pr & 15) * 4;
    int bn = bn0 + bl;
    f32x4 zs = {0.f, 0.f, 0.f, 0.f}, rs = {0.f, 0.f, 0.f, 0.f};
#pragma unroll
    for (int zz = 0; zz < 4; ++zz) {
      zs += up4(*(const bf16x4*)&P[((size_t)(zz * 128) + h) * MTOT + bn]);
      rs += up4(*(const bf16x4*)&P[((size_t)(zz * 128) + 64 + h) * MTOT + bn]);
    }
    f32x4 zv; bf16x4 cv;
#pragma unroll
    for (int j = 0; j < 4; ++j) {
      zv[j] = sigf(zs[j]);
      cv[j] = (bf16)(sigf(rs[j]) * st[h][bl + j]);
    }
    *(f32x4*)&zT[(size_t)h * MTOT + bn] = zv;
    int b = bn >> 11, n = bn & 2047;
    *(bf16x4*)&candT[(size_t)(b * 66 + 2 + h) * NND + n] = cv;
  }
}

// ---------------------------------------------------------------
// update epilogue (4 bf16 planes): out = (1-z)*state + z*tanh(sum)
// grid = MTOT/64
// ---------------------------------------------------------------
__global__ __launch_bounds__(256)
void update_epi(const bf16* __restrict__ P, const float* __restrict__ state,
                const float* __restrict__ zT, float* __restrict__ out) {
  __shared__ float st[64][65];
  int bn0 = blockIdx.x * 64;
  int t = threadIdx.x;
#pragma unroll
  for (int i = 0; i < 16; ++i) {
    int e = i * 256 + t;
    int bnr = e >> 6, oc = e & 63;
    st[oc][bnr] = state[(size_t)(bn0 + bnr) * 64 + oc];
  }
  __syncthreads();
#pragma unroll
  for (int i = 0; i < 4; ++i) {
    int pr = i * 256 + t;
    int o = pr >> 4, bl = (pr & 15) * 4;
    int bn = bn0 + bl;
    f32x4 ps = {0.f, 0.f, 0.f, 0.f};
#pragma unroll
    for (int zz = 0; zz < 4; ++zz)
      ps += up4(*(const bf16x4*)&P[((size_t)(zz * 64) + o) * MTOT + bn]);
    f32x4 zv = *(const f32x4*)&zT[(size_t)o * MTOT + bn];
#pragma unroll
    for (int j = 0; j < 4; ++j) {
      float hc = tanhf(ps[j]);
      float s0 = st[o][bl + j];
      st[o][bl + j] = (1.f - zv[j]) * s0 + zv[j] * hc;
    }
  }
  __syncthreads();
#pragma unroll
  for (int i = 0; i < 16; ++i) {
    int e = i * 256 + t;
    int bnr = e >> 6, oc = e & 63;
    out[(size_t)(bn0 + bnr) * 64 + oc] = st[oc][bnr];
  }
}

// ---------------------------------------------------------------
extern "C" void kernel_launch(void* const* d_in, const int* in_sizes, int n_in,
                              void* d_out, int out_size, void* d_ws, size_t ws_size,
                              hipStream_t stream) {
  const float* x     = (const float*)d_in[0];
  const float* state = (const float*)d_in[1];
  const float* E     = (const float*)d_in[2];
  const float* WpG   = (const float*)d_in[3];
  const float* BpG   = (const float*)d_in[4];
  const float* WpU   = (const float*)d_in[5];
  const float* BpU   = (const float*)d_in[6];
  float* out = (float*)d_out;

  char* p = (char*)d_ws;
  bf16*  Sbf   = (bf16*)p;  p += (size_t)NND * NND * 2;        // 8 MB
  bf16*  XT    = (bf16*)p;  p += (size_t)NPADC * NND * 2;      // 2.25 MB
  bf16*  candT = (bf16*)p;  p += (size_t)NPADC * NND * 2;      // 2.25 MB
  bf16*  Y1bf  = (bf16*)p;  p += (size_t)NPADC * NND * 2;      // 2.25 MB
  bf16*  Y2bf  = (bf16*)p;  p += (size_t)NPADC * NND * 2;      // 2.25 MB
  float* zT    = (float*)p; p += (size_t)64 * MTOT * 4;        // 4 MB
  bf16*  BTg   = (bf16*)p;  p += (size_t)128 * KEXP * 2;       // 832 KB
  bf16*  BTu   = (bf16*)p;  p += (size_t)64 * KEXP * 2;        // 416 KB
  bf16*  PP    = (bf16*)p;  p += (size_t)4 * 128 * MTOT * 2;   // 16.8 MB (graph+wgemm partials)

  dim3 b256(256);

  misc_kernel<<<PREP_BLKS + ADJ_BLKS + PACK_BLKS, b256, 0, stream>>>(
      E, x, state, WpG, BpG, WpU, BpU, Sbf, XT, candT, BTg, BTu);

  gemm_kernel<<<576, b256, 0, stream>>>(Sbf, XT, PP);
  reduce_kernel<<<576, b256, 0, stream>>>(PP, Y1bf);
  gemm_kernel<<<576, b256, 0, stream>>>(Sbf, Y1bf, PP);
  reduce_kernel<<<576, b256, 0, stream>>>(PP, Y2bf);
  wgemm_kernel<128><<<1024, b256, 0, stream>>>(XT, Y1bf, Y2bf, E, BTg, PP);
  gate_epi<<<MTOT / 64, b256, 0, stream>>>(PP, state, zT, candT);

  gemm_kernel<<<576, b256, 0, stream>>>(Sbf, candT, PP);
  reduce_kernel<<<576, b256, 0, stream>>>(PP, Y1bf);
  gemm_kernel<<<576, b256, 0, stream>>>(Sbf, Y1bf, PP);
  reduce_kernel<<<576, b256, 0, stream>>>(PP, Y2bf);
  wgemm_kernel<64><<<512, b256, 0, stream>>>(candT, Y1bf, Y2bf, E, BTu, PP);
  update_epi<<<MTOT / 64, b256, 0, stream>>>(PP, state, zT, out);
}

// Round 12
// 143.536 us; speedup vs baseline: 1.0847x; 1.0847x over previous
//
#include <hip/hip_runtime.h>

typedef __bf16 bf16;
typedef __bf16 bf16x8 __attribute__((ext_vector_type(8)));
typedef __bf16 bf16x4 __attribute__((ext_vector_type(4)));
typedef float  f32x4  __attribute__((ext_vector_type(4)));

#define NND   2048      // nodes
#define NBB   8         // batch
#define NPADC 576       // padded panel rows (>= 528, mult of 64)
#define KEXP  3328      // expanded K: 208 ki-chunks * 16 d
#define MTOT  16384     // B*N

__device__ __forceinline__ float sigf(float v) { return 1.f / (1.f + __expf(-v)); }

__device__ __forceinline__ void gl_lds16(const bf16* g, bf16* l) {
  __builtin_amdgcn_global_load_lds(
      (const __attribute__((address_space(1))) void*)g,
      (__attribute__((address_space(3))) void*)l, 16, 0, 0);
}

__device__ __forceinline__ f32x4 up4(bf16x4 v) {
  return __builtin_convertvector(v, f32x4);
}

// ---------------------------------------------------------------
// misc_kernel: grid-fused prep_w (156) + adj (256) + pack (256)
// ---------------------------------------------------------------
#define PREP_BLKS 156
#define ADJ_BLKS  256
#define PACK_BLKS 256

__global__ __launch_bounds__(256)
void misc_kernel(const float* __restrict__ E, const float* __restrict__ x,
                 const float* __restrict__ state,
                 const float* __restrict__ WpG, const float* __restrict__ BpG,
                 const float* __restrict__ WpU, const float* __restrict__ BpU,
                 bf16* __restrict__ Sbf, bf16* __restrict__ XT,
                 bf16* __restrict__ candT, bf16* __restrict__ BTg,
                 bf16* __restrict__ BTu) {
  __shared__ float tile[66][65];
  int bid = blockIdx.x;
  int t = threadIdx.x;

  if (bid < PREP_BLKS) {
    int which = bid / 52;
    int k0 = (bid % 52) * 64;
    const float* Wp; const float* Bp; bf16* BT; int ncols, o0;
    if (which < 2) { Wp = WpG; Bp = BpG; BT = BTg; ncols = 128; o0 = which * 64; }
    else           { Wp = WpU; Bp = BpU; BT = BTu; ncols = 64;  o0 = 0; }
    for (int idx = t; idx < 4096; idx += 256) {
      int kr = idx >> 6, oc = idx & 63;
      int kp = k0 + kr;
      int ki = kp >> 4, d = kp & 15;
      float v;
      if (ki < 198) {
        int kc3 = ki / 66;
        int i = ki - kc3 * 66;
        v = Wp[(size_t)((d * 3 + kc3) * 66 + i) * ncols + o0 + oc];
      } else if (ki == 198) {
        v = Bp[d * ncols + o0 + oc];
      } else {
        v = 0.f;
      }
      tile[kr][oc] = v;
    }
    __syncthreads();
    for (int idx = t; idx < 4096; idx += 256) {
      int orow = idx >> 6, kc = idx & 63;
      BT[(size_t)(o0 + orow) * KEXP + k0 + kc] = (bf16)tile[kc][orow];
    }
  } else if (bid < PREP_BLKS + ADJ_BLKS) {
    // adj: S = softmax(relu(E E^T)), 8 rows/block
    int r0 = (bid - PREP_BLKS) * 8;
    int lane = t & 63, w = t >> 6;
    float* red = &tile[0][0];
    float er[8][16];
#pragma unroll
    for (int r = 0; r < 8; ++r) {
      const f32x4* ep = (const f32x4*)(E + (size_t)(r0 + r) * 16);
#pragma unroll
      for (int qi = 0; qi < 4; ++qi) {
        f32x4 q = ep[qi];
#pragma unroll
        for (int j = 0; j < 4; ++j) er[r][qi * 4 + j] = q[j];
      }
    }
    float v[8][8];
    float mx[8];
#pragma unroll
    for (int r = 0; r < 8; ++r) mx[r] = 0.f;
#pragma unroll
    for (int j = 0; j < 8; ++j) {
      int c = t + j * 256;
      const f32x4* cp = (const f32x4*)(E + (size_t)c * 16);
      float ec[16];
#pragma unroll
      for (int qi = 0; qi < 4; ++qi) {
        f32x4 q = cp[qi];
#pragma unroll
        for (int jj = 0; jj < 4; ++jj) ec[qi * 4 + jj] = q[jj];
      }
#pragma unroll
      for (int r = 0; r < 8; ++r) {
        float s = 0.f;
#pragma unroll
        for (int d = 0; d < 16; ++d) s += er[r][d] * ec[d];
        s = fmaxf(s, 0.f);
        v[r][j] = s;
        mx[r] = fmaxf(mx[r], s);
      }
    }
#pragma unroll
    for (int o = 32; o > 0; o >>= 1)
#pragma unroll
      for (int r = 0; r < 8; ++r) mx[r] = fmaxf(mx[r], __shfl_xor(mx[r], o, 64));
    if (lane == 0)
#pragma unroll
      for (int r = 0; r < 8; ++r) red[w * 8 + r] = mx[r];
    __syncthreads();
#pragma unroll
    for (int r = 0; r < 8; ++r)
      mx[r] = fmaxf(fmaxf(red[r], red[8 + r]), fmaxf(red[16 + r], red[24 + r]));
    float sm[8];
#pragma unroll
    for (int r = 0; r < 8; ++r) sm[r] = 0.f;
#pragma unroll
    for (int j = 0; j < 8; ++j)
#pragma unroll
      for (int r = 0; r < 8; ++r) { v[r][j] = __expf(v[r][j] - mx[r]); sm[r] += v[r][j]; }
#pragma unroll
    for (int o = 32; o > 0; o >>= 1)
#pragma unroll
      for (int r = 0; r < 8; ++r) sm[r] += __shfl_xor(sm[r], o, 64);
    __syncthreads();
    if (lane == 0)
#pragma unroll
      for (int r = 0; r < 8; ++r) red[32 + w * 8 + r] = sm[r];
    __syncthreads();
#pragma unroll
    for (int r = 0; r < 8; ++r) {
      float inv = 1.f / (red[32 + r] + red[40 + r] + red[48 + r] + red[56 + r]);
#pragma unroll
      for (int j = 0; j < 8; ++j)
        Sbf[(size_t)(r0 + r) * NND + t + j * 256] = (bf16)(v[r][j] * inv);
    }
  } else {
    // pack: XT[(b*66+c)][n] = concat(x,state); x-rows also -> candT
    int pb = bid - PREP_BLKS - ADJ_BLKS;
    int b  = pb >> 5;
    int n0 = (pb & 31) * 64;
    for (int idx = t; idx < 66 * 64; idx += 256) {
      int nn = idx / 66;
      int c  = idx - nn * 66;
      int bn = (b << 11) + n0 + nn;
      float v = (c < 2) ? x[bn * 2 + c] : state[(bn << 6) + c - 2];
      tile[c][nn] = v;
    }
    __syncthreads();
    for (int idx = t; idx < 66 * 64; idx += 256) {
      int c = idx >> 6;
      int nn = idx & 63;
      bf16 v = (bf16)tile[c][nn];
      size_t off = (size_t)(b * 66 + c) * NND + n0 + nn;
      XT[off] = v;
      if (c < 2) candT[off] = v;
    }
  }
}

// ---------------------------------------------------------------
// graph GEMM partials (bf16): P[z][c][n] = sum_{z-quarter} S[n][k]*B[c][k]
// 128(n) x 64(c) tile, BK=64, gl_lds + XOR swizzle, dbuf, 1 barrier/step.
// 1D grid 576 with XCD chunk swizzle, m-major.
// ---------------------------------------------------------------
__global__ __launch_bounds__(256)
void gemm_kernel(const bf16* __restrict__ A, const bf16* __restrict__ Bbf,
                 bf16* __restrict__ P) {
  __shared__ bf16 As[2][128 * 64];
  __shared__ bf16 Bs[2][64 * 64];
  int t = threadIdx.x;
  int wg = (blockIdx.x & 7) * 72 + (blockIdx.x >> 3);   // 576 = 8*72, bijective
  int m  = wg / 36;
  int rem = wg - m * 36;
  int m0 = m * 128;
  int c0 = (rem >> 2) * 64;
  int z  = rem & 3;
  int lane = t & 63, w = t >> 6;
  int wr = w >> 1, wc = w & 1;
  int row16 = lane & 15, kq = (lane >> 4) << 3;
  int kbase = z * 512;

  f32x4 acc[4][2] = {};

  auto stage = [&](int k0, int bb) {
#pragma unroll
    for (int i = 0; i < 4; ++i) {
      int s = i * 256 + t;
      int row = s >> 3;
      int g = ((s & 7) ^ (row & 7)) << 3;
      gl_lds16(A + (size_t)(m0 + row) * NND + k0 + g, &As[bb][s * 8]);
    }
#pragma unroll
    for (int i = 0; i < 2; ++i) {
      int s = i * 256 + t;
      int row = s >> 3;
      int g = ((s & 7) ^ (row & 7)) << 3;
      gl_lds16(Bbf + (size_t)(c0 + row) * NND + k0 + g, &Bs[bb][s * 8]);
    }
  };
  auto mstep = [&](int bb) {
#pragma unroll
    for (int kk2 = 0; kk2 < 64; kk2 += 32) {
      int kcg = (kk2 + kq) >> 3;
      bf16x8 af[4], bfg[2];
#pragma unroll
      for (int mi = 0; mi < 4; ++mi) {
        int row = wr * 64 + mi * 16 + row16;
        af[mi] = *(const bf16x8*)&As[bb][row * 64 + ((kcg ^ (row & 7)) << 3)];
      }
#pragma unroll
      for (int ni = 0; ni < 2; ++ni) {
        int row = wc * 32 + ni * 16 + row16;
        bfg[ni] = *(const bf16x8*)&Bs[bb][row * 64 + ((kcg ^ (row & 7)) << 3)];
      }
#pragma unroll
      for (int mi = 0; mi < 4; ++mi)
#pragma unroll
        for (int ni = 0; ni < 2; ++ni)
          acc[mi][ni] = __builtin_amdgcn_mfma_f32_16x16x32_bf16(af[mi], bfg[ni], acc[mi][ni], 0, 0, 0);
    }
  };

  stage(kbase, 0);
  __syncthreads();
  int buf = 0;
  for (int s = 0; s < 8; ++s) {
    if (s < 7) stage(kbase + (s + 1) * 64, buf ^ 1);
    mstep(buf);
    __syncthreads();
    buf ^= 1;
  }

#pragma unroll
  for (int mi = 0; mi < 4; ++mi)
#pragma unroll
    for (int ni = 0; ni < 2; ++ni) {
      int nb = m0 + wr * 64 + mi * 16 + ((lane >> 4) << 2);
      int oc = c0 + wc * 32 + ni * 16 + (lane & 15);
      bf16x4 pb = __builtin_convertvector(acc[mi][ni], bf16x4);
      *(bf16x4*)&P[((size_t)z * NPADC + oc) * NND + nb] = pb;
    }
}

// ---------------------------------------------------------------
// reduce_sum: Y = bf16(sum of 4 bf16 planes). grid 576.
// ---------------------------------------------------------------
__global__ __launch_bounds__(256)
void reduce_sum(const bf16* __restrict__ P, bf16* __restrict__ Y) {
  size_t i = ((size_t)blockIdx.x * 256 + threadIdx.x) * 8;
  const size_t PL = (size_t)NPADC * NND;
  bf16x8 p0 = *(const bf16x8*)&P[i];
  bf16x8 p1 = *(const bf16x8*)&P[PL + i];
  bf16x8 p2 = *(const bf16x8*)&P[2 * PL + i];
  bf16x8 p3 = *(const bf16x8*)&P[3 * PL + i];
  bf16x8 o;
#pragma unroll
  for (int j = 0; j < 8; ++j)
    o[j] = (bf16)(((float)p0[j] + (float)p1[j]) + ((float)p2[j] + (float)p3[j]));
  *(bf16x8*)&Y[i] = o;
}

// ---------------------------------------------------------------
// reduce_cheb: C2 = bf16(2*sum(planes) - Xsrc)  (fuses the Chebyshev
// combine so wgemm's ki<198 branch is a single load). grid 576.
// ---------------------------------------------------------------
__global__ __launch_bounds__(256)
void reduce_cheb(const bf16* __restrict__ P, const bf16* __restrict__ Xsrc,
                 bf16* __restrict__ C2) {
  size_t i = ((size_t)blockIdx.x * 256 + threadIdx.x) * 8;
  const size_t PL = (size_t)NPADC * NND;
  bf16x8 p0 = *(const bf16x8*)&P[i];
  bf16x8 p1 = *(const bf16x8*)&P[PL + i];
  bf16x8 p2 = *(const bf16x8*)&P[2 * PL + i];
  bf16x8 p3 = *(const bf16x8*)&P[3 * PL + i];
  bf16x8 xs = *(const bf16x8*)&Xsrc[i];
  bf16x8 o;
#pragma unroll
  for (int j = 0; j < 8; ++j)
    o[j] = (bf16)(2.f * (((float)p0[j] + (float)p1[j]) + ((float)p2[j] + (float)p3[j]))
                  - (float)xs[j]);
  *(bf16x8*)&C2[i] = o;
}

// ---------------------------------------------------------------
// wgemm partials (bf16): Pg[z][oc][bn] = sum_{z-quarter} A'[bn][k]*B'[k][oc]
// A'[bn][ki*16+d] = xg(bn,ki)*E[n][d] built in LDS (swizzled ds_write).
// 64(bn) x 64(oc) tile, BK=64, 13 steps, ONE barrier/step, 32KB LDS
// (5 blocks/CU). Depth-2 xg prefetch: loadx(s+2) issued at iter s,
// consumed by expand at iter s+1 — xg latency spans two steps.
// 1D grid with XCD swizzle: gate 2048 blocks, update 1024.
// ---------------------------------------------------------------
template<int NCOLS>
__global__ __launch_bounds__(256)
void wgemm_kernel(const bf16* __restrict__ XTsrc, const bf16* __restrict__ Y1,
                  const bf16* __restrict__ C2, const float* __restrict__ E,
                  const bf16* __restrict__ BT, bf16* __restrict__ Pg) {
  constexpr int YB  = NCOLS / 64;
  constexpr int NWG = (MTOT / 64) * YB * 4;
  __shared__ bf16 As[2][64 * 64];
  __shared__ bf16 Bs[2][64 * 64];
  int t = threadIdx.x;
  int wg = (blockIdx.x & 7) * (NWG >> 3) + (blockIdx.x >> 3);
  int z  = wg & 3;
  int y  = (wg >> 2) % YB;
  int m0 = (wg / (4 * YB)) * 64;
  int oc0 = y * 64;
  const bf16* BTb = BT + (size_t)oc0 * KEXP;
  int lane = t & 63, w = t >> 6;
  int wr = w >> 1, wc = w & 1;
  int row16 = lane & 15, kq = (lane >> 4) << 3;
  int r = t & 63, kh = t >> 6;             // expansion: row r, ki-slot kh (0..3)
  int bn = m0 + r, bidx = bn >> 11, n = bn & 2047;
  const int kbase = z * 832, kibase = z * 52;

  float e[16];
  {
    const f32x4* ep = (const f32x4*)(E + (size_t)n * 16);
#pragma unroll
    for (int qi = 0; qi < 4; ++qi) {
      f32x4 q = ep[qi];
#pragma unroll
      for (int j = 0; j < 4; ++j) e[qi * 4 + j] = q[j];
    }
  }

  f32x4 acc[2][2] = {};

  auto loadx = [&](int ki) -> float {
    if (ki < 66)  return (float)XTsrc[(size_t)(bidx * 66 + ki) * NND + n];
    if (ki < 132) return (float)Y1[(size_t)(bidx * 66 + ki - 66) * NND + n];
    if (ki < 198) return (float)C2[(size_t)(bidx * 66 + ki - 132) * NND + n];
    return (ki == 198) ? 1.f : 0.f;
  };
  auto expand = [&](int bb, float xv) {
#pragma unroll
    for (int p = 0; p < 2; ++p) {
      bf16x8 pk;
#pragma unroll
      for (int j = 0; j < 8; ++j) pk[j] = (bf16)(xv * e[p * 8 + j]);
      int g = kh * 2 + p;
      *(bf16x8*)&As[bb][r * 64 + ((g ^ (r & 7)) << 3)] = pk;
    }
  };
  auto stageB = [&](int k0, int bb) {
#pragma unroll
    for (int i = 0; i < 2; ++i) {
      int s = i * 256 + t;
      int row = s >> 3;
      int g = ((s & 7) ^ (row & 7)) << 3;
      gl_lds16(BTb + (size_t)row * KEXP + k0 + g, &Bs[bb][s * 8]);
    }
  };
  auto mstep = [&](int bb) {
#pragma unroll
    for (int kk2 = 0; kk2 < 64; kk2 += 32) {
      int kcg = (kk2 + kq) >> 3;
      bf16x8 af[2], bfg[2];
#pragma unroll
      for (int mi = 0; mi < 2; ++mi) {
        int row = wr * 32 + mi * 16 + row16;
        af[mi] = *(const bf16x8*)&As[bb][row * 64 + ((kcg ^ (row & 7)) << 3)];
      }
#pragma unroll
      for (int ni = 0; ni < 2; ++ni) {
        int row = wc * 32 + ni * 16 + row16;
        bfg[ni] = *(const bf16x8*)&Bs[bb][row * 64 + ((kcg ^ (row & 7)) << 3)];
      }
#pragma unroll
      for (int mi = 0; mi < 2; ++mi)
#pragma unroll
        for (int ni = 0; ni < 2; ++ni)
          acc[mi][ni] = __builtin_amdgcn_mfma_f32_16x16x32_bf16(af[mi], bfg[ni], acc[mi][ni], 0, 0, 0);
    }
  };

  // prologue: stage step 0 into buf 0; preload xg for step 1
  float xa;
  {
    float xv0 = loadx(kibase + kh);
    stageB(kbase, 0);
    expand(0, xv0);
    xa = loadx(kibase + 4 + kh);     // xg for step 1, consumed at iter 0
  }
  __syncthreads();

  int buf = 0;
  for (int s = 0; s < 13; ++s) {
    float xb = 0.f;
    if (s < 11) xb = loadx(kibase + (s + 2) * 4 + kh);  // xg(s+2), 2 steps ahead
    if (s < 12) stageB(kbase + (s + 1) * 64, buf ^ 1);  // gl_lds into Bs[buf^1]
    mstep(buf);                                // reads As/Bs[buf] only
    if (s < 12) expand(buf ^ 1, xa);           // xa = xg(s+1), loaded at iter s-1
    __syncthreads();                           // one barrier/step
    xa = xb;
    buf ^= 1;
  }

#pragma unroll
  for (int mi = 0; mi < 2; ++mi)
#pragma unroll
    for (int ni = 0; ni < 2; ++ni) {
      int nb = m0 + wr * 32 + mi * 16 + ((lane >> 4) << 2);
      int oc = oc0 + wc * 32 + ni * 16 + (lane & 15);
      bf16x4 pb = __builtin_convertvector(acc[mi][ni], bf16x4);
      *(bf16x4*)&Pg[((size_t)z * NCOLS + oc) * MTOT + nb] = pb;
    }
}

// ---------------------------------------------------------------
// gate epilogue (4 bf16 planes): zT = sig(sum); candT = sig(sum)*state
// grid = MTOT/64
// ---------------------------------------------------------------
__global__ __launch_bounds__(256)
void gate_epi(const bf16* __restrict__ P, const float* __restrict__ state,
              float* __restrict__ zT, bf16* __restrict__ candT) {
  __shared__ float st[64][65];
  int bn0 = blockIdx.x * 64;
  int t = threadIdx.x;
#pragma unroll
  for (int i = 0; i < 16; ++i) {
    int e = i * 256 + t;
    int bnr = e >> 6, hc = e & 63;
    st[hc][bnr] = state[(size_t)(bn0 + bnr) * 64 + hc];
  }
  __syncthreads();
#pragma unroll
  for (int i = 0; i < 4; ++i) {
    int pr = i * 256 + t;
    int h = pr >> 4, bl = (pr & 15) * 4;
    int bn = bn0 + bl;
    f32x4 zs = {0.f, 0.f, 0.f, 0.f}, rs = {0.f, 0.f, 0.f, 0.f};
#pragma unroll
    for (int zz = 0; zz < 4; ++zz) {
      zs += up4(*(const bf16x4*)&P[((size_t)(zz * 128) + h) * MTOT + bn]);
      rs += up4(*(const bf16x4*)&P[((size_t)(zz * 128) + 64 + h) * MTOT + bn]);
    }
    f32x4 zv; bf16x4 cv;
#pragma unroll
    for (int j = 0; j < 4; ++j) {
      zv[j] = sigf(zs[j]);
      cv[j] = (bf16)(sigf(rs[j]) * st[h][bl + j]);
    }
    *(f32x4*)&zT[(size_t)h * MTOT + bn] = zv;
    int b = bn >> 11, n = bn & 2047;
    *(bf16x4*)&candT[(size_t)(b * 66 + 2 + h) * NND + n] = cv;
  }
}

// ---------------------------------------------------------------
// update epilogue (4 bf16 planes): out = (1-z)*state + z*tanh(sum)
// grid = MTOT/64
// ---------------------------------------------------------------
__global__ __launch_bounds__(256)
void update_epi(const bf16* __restrict__ P, const float* __restrict__ state,
                const float* __restrict__ zT, float* __restrict__ out) {
  __shared__ float st[64][65];
  int bn0 = blockIdx.x * 64;
  int t = threadIdx.x;
#pragma unroll
  for (int i = 0; i < 16; ++i) {
    int e = i * 256 + t;
    int bnr = e >> 6, oc = e & 63;
    st[oc][bnr] = state[(size_t)(bn0 + bnr) * 64 + oc];
  }
  __syncthreads();
#pragma unroll
  for (int i = 0; i < 4; ++i) {
    int pr = i * 256 + t;
    int o = pr >> 4, bl = (pr & 15) * 4;
    int bn = bn0 + bl;
    f32x4 ps = {0.f, 0.f, 0.f, 0.f};
#pragma unroll
    for (int zz = 0; zz < 4; ++zz)
      ps += up4(*(const bf16x4*)&P[((size_t)(zz * 64) + o) * MTOT + bn]);
    f32x4 zv = *(const f32x4*)&zT[(size_t)o * MTOT + bn];
#pragma unroll
    for (int j = 0; j < 4; ++j) {
      float hc = tanhf(ps[j]);
      float s0 = st[o][bl + j];
      st[o][bl + j] = (1.f - zv[j]) * s0 + zv[j] * hc;
    }
  }
  __syncthreads();
#pragma unroll
  for (int i = 0; i < 16; ++i) {
    int e = i * 256 + t;
    int bnr = e >> 6, oc = e & 63;
    out[(size_t)(bn0 + bnr) * 64 + oc] = st[oc][bnr];
  }
}

// ---------------------------------------------------------------
extern "C" void kernel_launch(void* const* d_in, const int* in_sizes, int n_in,
                              void* d_out, int out_size, void* d_ws, size_t ws_size,
                              hipStream_t stream) {
  const float* x     = (const float*)d_in[0];
  const float* state = (const float*)d_in[1];
  const float* E     = (const float*)d_in[2];
  const float* WpG   = (const float*)d_in[3];
  const float* BpG   = (const float*)d_in[4];
  const float* WpU   = (const float*)d_in[5];
  const float* BpU   = (const float*)d_in[6];
  float* out = (float*)d_out;

  char* p = (char*)d_ws;
  bf16*  Sbf   = (bf16*)p;  p += (size_t)NND * NND * 2;        // 8 MB
  bf16*  XT    = (bf16*)p;  p += (size_t)NPADC * NND * 2;      // 2.25 MB
  bf16*  candT = (bf16*)p;  p += (size_t)NPADC * NND * 2;      // 2.25 MB
  bf16*  Y1bf  = (bf16*)p;  p += (size_t)NPADC * NND * 2;      // 2.25 MB
  bf16*  C2bf  = (bf16*)p;  p += (size_t)NPADC * NND * 2;      // 2.25 MB (2*Y2 - X)
  float* zT    = (float*)p; p += (size_t)64 * MTOT * 4;        // 4 MB
  bf16*  BTg   = (bf16*)p;  p += (size_t)128 * KEXP * 2;       // 832 KB
  bf16*  BTu   = (bf16*)p;  p += (size_t)64 * KEXP * 2;        // 416 KB
  bf16*  PP    = (bf16*)p;  p += (size_t)4 * 128 * MTOT * 2;   // 16.8 MB (graph+wgemm partials)

  dim3 b256(256);

  misc_kernel<<<PREP_BLKS + ADJ_BLKS + PACK_BLKS, b256, 0, stream>>>(
      E, x, state, WpG, BpG, WpU, BpU, Sbf, XT, candT, BTg, BTu);

  gemm_kernel<<<576, b256, 0, stream>>>(Sbf, XT, PP);
  reduce_sum<<<576, b256, 0, stream>>>(PP, Y1bf);
  gemm_kernel<<<576, b256, 0, stream>>>(Sbf, Y1bf, PP);
  reduce_cheb<<<576, b256, 0, stream>>>(PP, XT, C2bf);
  wgemm_kernel<128><<<2048, b256, 0, stream>>>(XT, Y1bf, C2bf, E, BTg, PP);
  gate_epi<<<MTOT / 64, b256, 0, stream>>>(PP, state, zT, candT);

  gemm_kernel<<<576, b256, 0, stream>>>(Sbf, candT, PP);
  reduce_sum<<<576, b256, 0, stream>>>(PP, Y1bf);
  gemm_kernel<<<576, b256, 0, stream>>>(Sbf, Y1bf, PP);
  reduce_cheb<<<576, b256, 0, stream>>>(PP, candT, C2bf);
  wgemm_kernel<64><<<1024, b256, 0, stream>>>(candT, Y1bf, C2bf, E, BTu, PP);
  update_epi<<<MTOT / 64, b256, 0, stream>>>(PP, state, zT, out);
}